// Round 1
// baseline (668.365 us; speedup 1.0000x reference)
//
#include <hip/hip_runtime.h>

#define EMB 2048
#define NH 16
#define NKV 4
#define HD 128
#define SLEN 2048
#define BSZ 2
#define MROWS (BSZ * SLEN) // 4096

typedef __attribute__((ext_vector_type(8))) short bf16x8;
typedef __attribute__((ext_vector_type(4))) float f32x4;
typedef __attribute__((ext_vector_type(2))) float f32x2;
typedef __attribute__((ext_vector_type(4))) short s16x4;

__device__ __forceinline__ short f2bf(float f) {
  union { float f; unsigned u; } v; v.f = f;
  unsigned r = (v.u + 0x7fffu + ((v.u >> 16) & 1u)) >> 16;
  return (short)r;
}

// ---------------- RoPE cos/sin table: [SLEN][64] ----------------
__global__ void rope_tab_k(f32x2* __restrict__ tab) {
  int i = blockIdx.x * blockDim.x + threadIdx.x;
  if (i >= SLEN * 64) return;
  int s = i >> 6, j = i & 63;
  // freq = 10000^(-2j/128) = 2^(-(j/64)*log2(10000))
  float freq = exp2f(-(float)j * (13.287712379549449f / 64.0f));
  float ang = (float)s * freq;
  float sv, cv;
  sincosf(ang, &sv, &cv);
  f32x2 cs; cs[0] = cv; cs[1] = sv;
  tab[i] = cs;
}

// ---------------- fp32 -> bf16 cast (vectorized) ----------------
__global__ void cast_bf16_k(const float* __restrict__ in, short* __restrict__ outp, int n) {
  int i = (blockIdx.x * blockDim.x + threadIdx.x) * 4;
  if (i >= n) return;
  f32x4 v = *(const f32x4*)(in + i);
  s16x4 r;
#pragma unroll
  for (int k = 0; k < 4; ++k) r[k] = f2bf(v[k]);
  *(s16x4*)(outp + i) = r;
}

// ---------------- transpose + cast: in (R,C) fp32 -> out (C,R) bf16 ----------------
__global__ void transpose_cast_k(const float* __restrict__ in, short* __restrict__ outp,
                                 int R, int C) {
  __shared__ float t[32][33];
  int c0 = blockIdx.x * 32, r0 = blockIdx.y * 32;
  int tx = threadIdx.x, ty = threadIdx.y; // 32 x 8
#pragma unroll
  for (int i = 0; i < 4; ++i)
    t[ty + i * 8][tx] = in[(size_t)(r0 + ty + i * 8) * C + (c0 + tx)];
  __syncthreads();
#pragma unroll
  for (int i = 0; i < 4; ++i)
    outp[(size_t)(c0 + ty + i * 8) * R + (r0 + tx)] = f2bf(t[tx][ty + i * 8]);
}

// ---------------- GEMM: C(M,N) = A(M,K) * Bt(N,K)^T, bf16 MFMA ----------------
#define BM 128
#define BN 128
#define BK 32

#define GLL16(g, l)                                                        \
  __builtin_amdgcn_global_load_lds(                                        \
      (const __attribute__((address_space(1))) void*)(g),                  \
      (__attribute__((address_space(3))) void*)(l), 16, 0, 0)

// EPI: 0 = fp32 store to Cf (row-major M x N)
//      1 = RoPE + store Q bf16 as [B][NH][S][HD]
//      2 = RoPE + store K bf16 as [B][NKV][S][HD]
//      3 = store V bf16 transposed as [B][NKV][HD][S]
template <int EPI>
__global__ __launch_bounds__(256, 2) void gemm_bt_k(
    const short* __restrict__ A, const short* __restrict__ Bt,
    float* __restrict__ Cf, short* __restrict__ Cb,
    int M, int N, int K, const f32x2* __restrict__ rope) {
  __shared__ short lA[2][BM * BK];
  __shared__ short lB[2][BN * BK];
  int tid = threadIdx.x;
  int lane = tid & 63, wid = tid >> 6;
  int m0 = blockIdx.y * BM, n0 = blockIdx.x * BN;
  int wr = (wid >> 1) * 64, wc = (wid & 1) * 64;
  int l16 = lane & 15, lk = (lane >> 4) * 8;
  (void)M;

  auto stage = [&](int buf, int k0) {
    const short* ga = A + (size_t)m0 * K + k0;
    const short* gb = Bt + (size_t)n0 * K + k0;
#pragma unroll
    for (int i = 0; i < 2; ++i) {
      int cidx = i * 256 + tid;
      int row = cidx >> 2, c8 = (cidx & 3) << 3;
      GLL16(ga + (size_t)row * K + c8, &lA[buf][(size_t)(i * 256 + (tid & 192)) * 8]);
      GLL16(gb + (size_t)row * K + c8, &lB[buf][(size_t)(i * 256 + (tid & 192)) * 8]);
    }
  };

  f32x4 acc[4][4] = {};
  stage(0, 0);
  asm volatile("s_waitcnt vmcnt(0)" ::: "memory");
  __syncthreads();
  int nk = K / BK;
  for (int t = 0; t < nk; ++t) {
    int buf = t & 1;
    if (t + 1 < nk) stage(buf ^ 1, (t + 1) * BK);
    bf16x8 af[4], bfv[4];
#pragma unroll
    for (int m = 0; m < 4; ++m)
      af[m] = *(const bf16x8*)&lA[buf][(wr + m * 16 + l16) * BK + lk];
#pragma unroll
    for (int n = 0; n < 4; ++n)
      bfv[n] = *(const bf16x8*)&lB[buf][(wc + n * 16 + l16) * BK + lk];
#pragma unroll
    for (int m = 0; m < 4; ++m)
#pragma unroll
      for (int n = 0; n < 4; ++n)
        acc[m][n] = __builtin_amdgcn_mfma_f32_16x16x32_bf16(af[m], bfv[n], acc[m][n], 0, 0, 0);
    asm volatile("s_waitcnt vmcnt(0)" ::: "memory");
    __syncthreads();
  }

  // epilogue: C/D layout col = lane&15, row = (lane>>4)*4 + reg
#pragma unroll
  for (int m = 0; m < 4; ++m) {
#pragma unroll
    for (int n = 0; n < 4; ++n) {
#pragma unroll
      for (int j = 0; j < 4; ++j) {
        int gm = m0 + wr + m * 16 + (lane >> 4) * 4 + j;
        int gc = n0 + wc + n * 16 + l16;
        float v = acc[m][n][j];
        if constexpr (EPI == 0) {
          Cf[(size_t)gm * N + gc] = v;
        } else if constexpr (EPI == 1 || EPI == 2) {
          float p = __shfl_xor(v, 1); // partner column (d^1), same row
          int pos = gm & (SLEN - 1), bb = gm >> 11;
          int head = gc >> 7, d = gc & 127, j2 = d >> 1;
          f32x2 cs = rope[pos * 64 + j2];
          float ov; int od;
          if ((d & 1) == 0) { ov = v * cs[0] - p * cs[1]; od = j2; }        // x1*cos - x2*sin
          else              { ov = p * cs[1] + v * cs[0]; od = j2 + 64; }   // x1*sin + x2*cos
          const int nh = (EPI == 1) ? NH : NKV;
          Cb[((size_t)(bb * nh + head) * SLEN + pos) * HD + od] = f2bf(ov);
        } else { // EPI == 3: V transposed per (b,kv): [HD][S]
          int pos = gm & (SLEN - 1), bb = gm >> 11;
          int head = gc >> 7, d = gc & 127;
          Cb[((size_t)(bb * NKV + head) * HD + d) * SLEN + pos] = f2bf(v);
        }
      }
    }
  }
}

// ---------------- flash attention (causal, GQA via tile: kv = h % 4) ----------------
__global__ __launch_bounds__(256, 2) void flash_k(
    const short* __restrict__ Qb, const short* __restrict__ Kb,
    const short* __restrict__ Vt, short* __restrict__ O) {
  int tid = threadIdx.x, lane = tid & 63, wid = tid >> 6;
  int qt = blockIdx.x, bh = blockIdx.y;
  int b = bh >> 4, h = bh & 15, kv = h & 3; // jnp.tile => h % NKV
  int l16 = lane & 15, lk4 = lane >> 4;
  int qb = qt * 64 + wid * 16;

  const short* qptr = Qb + (size_t)(b * NH + h) * SLEN * HD;
  const short* kptr = Kb + (size_t)(b * NKV + kv) * SLEN * HD;
  const short* vptr = Vt + (size_t)(b * NKV + kv) * HD * SLEN;

  bf16x8 aq[4];
#pragma unroll
  for (int c = 0; c < 4; ++c)
    aq[c] = *(const bf16x8*)(qptr + (size_t)(qb + l16) * HD + c * 32 + lk4 * 8);

  f32x4 o[8] = {};
  float ninf = -__builtin_inff();
  float mrow[4] = { ninf, ninf, ninf, ninf };
  float lrow[4] = {};

  __shared__ short Plds[4][16][32];
  short (*myP)[32] = Plds[wid];

  const float sc = 0.08838834764831845f; // 1/sqrt(128)
  const float L2E = 1.4426950408889634f;

  int kend = qt * 64 + 64;
  for (int k0 = 0; k0 < kend; k0 += 32) {
    f32x4 s[2] = {};
#pragma unroll
    for (int c = 0; c < 4; ++c) {
      bf16x8 bk0 = *(const bf16x8*)(kptr + (size_t)(k0 + l16) * HD + c * 32 + lk4 * 8);
      bf16x8 bk1 = *(const bf16x8*)(kptr + (size_t)(k0 + 16 + l16) * HD + c * 32 + lk4 * 8);
      s[0] = __builtin_amdgcn_mfma_f32_16x16x32_bf16(aq[c], bk0, s[0], 0, 0, 0);
      s[1] = __builtin_amdgcn_mfma_f32_16x16x32_bf16(aq[c], bk1, s[1], 0, 0, 0);
    }
#pragma unroll
    for (int j = 0; j < 4; ++j) {
      int q = qb + lk4 * 4 + j;
      float v0 = s[0][j] * sc;
      float v1 = s[1][j] * sc;
      if (k0 + l16 > q)      v0 = -3.0e38f;
      if (k0 + 16 + l16 > q) v1 = -3.0e38f;
      float t = fmaxf(v0, v1);
      t = fmaxf(t, __shfl_xor(t, 1));
      t = fmaxf(t, __shfl_xor(t, 2));
      t = fmaxf(t, __shfl_xor(t, 4));
      t = fmaxf(t, __shfl_xor(t, 8));
      float mn = fmaxf(mrow[j], t);
      float f = exp2f((mrow[j] - mn) * L2E);
      mrow[j] = mn;
      float p0 = exp2f((v0 - mn) * L2E);
      float p1 = exp2f((v1 - mn) * L2E);
      float ps = p0 + p1;
      ps += __shfl_xor(ps, 1);
      ps += __shfl_xor(ps, 2);
      ps += __shfl_xor(ps, 4);
      ps += __shfl_xor(ps, 8);
      lrow[j] = lrow[j] * f + ps;
#pragma unroll
      for (int dt = 0; dt < 8; ++dt) o[dt][j] *= f;
      myP[lk4 * 4 + j][l16] = f2bf(p0);
      myP[lk4 * 4 + j][16 + l16] = f2bf(p1);
    }
    asm volatile("s_waitcnt lgkmcnt(0)" ::: "memory");
    __builtin_amdgcn_sched_barrier(0);
    bf16x8 pa = *(const bf16x8*)&myP[l16][lk4 * 8];
#pragma unroll
    for (int dt = 0; dt < 8; ++dt) {
      bf16x8 bv = *(const bf16x8*)(vptr + (size_t)(dt * 16 + l16) * SLEN + k0 + lk4 * 8);
      o[dt] = __builtin_amdgcn_mfma_f32_16x16x32_bf16(pa, bv, o[dt], 0, 0, 0);
    }
  }
#pragma unroll
  for (int j = 0; j < 4; ++j) {
    float inv = 1.0f / lrow[j];
    int q = qb + lk4 * 4 + j;
    size_t ro = ((size_t)(b * SLEN + q)) * (NH * HD) + h * HD;
#pragma unroll
    for (int dt = 0; dt < 8; ++dt)
      O[ro + dt * 16 + l16] = f2bf(o[dt][j] * inv);
  }
}

extern "C" void kernel_launch(void* const* d_in, const int* in_sizes, int n_in,
                              void* d_out, int out_size, void* d_ws, size_t ws_size,
                              hipStream_t stream) {
  const float* x  = (const float*)d_in[0];
  const float* wq = (const float*)d_in[1];
  const float* wk = (const float*)d_in[2];
  const float* wv = (const float*)d_in[3];
  const float* wo = (const float*)d_in[4];
  float* out = (float*)d_out;
  char* ws = (char*)d_ws;
  (void)in_sizes; (void)n_in; (void)out_size; (void)ws_size;

  const size_t MB = 1024 * 1024;
  f32x2* rope = (f32x2*)(ws);            // 1 MB
  short* xb  = (short*)(ws + 1 * MB);    // 16 MB (reused as O)
  short* wqT = (short*)(ws + 17 * MB);   // 8 MB
  short* wkT = (short*)(ws + 25 * MB);   // 2 MB
  short* wvT = (short*)(ws + 27 * MB);   // 2 MB
  short* woT = (short*)(ws + 29 * MB);   // 8 MB
  short* Qb  = (short*)(ws + 37 * MB);   // 16 MB
  short* Kb  = (short*)(ws + 53 * MB);   // 4 MB
  short* Vt  = (short*)(ws + 57 * MB);   // 4 MB
  short* O   = xb;                       // alias: xb dead after V GEMM

  rope_tab_k<<<(SLEN * 64 + 255) / 256, 256, 0, stream>>>(rope);
  cast_bf16_k<<<(MROWS * EMB / 4 + 255) / 256, 256, 0, stream>>>(x, xb, MROWS * EMB);

  dim3 tb(32, 8);
  transpose_cast_k<<<dim3(2048 / 32, 2048 / 32), tb, 0, stream>>>(wq, wqT, 2048, 2048);
  transpose_cast_k<<<dim3(512 / 32, 2048 / 32), tb, 0, stream>>>(wk, wkT, 2048, 512);
  transpose_cast_k<<<dim3(512 / 32, 2048 / 32), tb, 0, stream>>>(wv, wvT, 2048, 512);
  transpose_cast_k<<<dim3(2048 / 32, 2048 / 32), tb, 0, stream>>>(wo, woT, 2048, 2048);

  gemm_bt_k<1><<<dim3(2048 / BN, MROWS / BM), 256, 0, stream>>>(xb, wqT, nullptr, Qb, MROWS, 2048, 2048, rope);
  gemm_bt_k<2><<<dim3(512 / BN, MROWS / BM), 256, 0, stream>>>(xb, wkT, nullptr, Kb, MROWS, 512, 2048, rope);
  gemm_bt_k<3><<<dim3(512 / BN, MROWS / BM), 256, 0, stream>>>(xb, wvT, nullptr, Vt, MROWS, 512, 2048, rope);

  flash_k<<<dim3(SLEN / 64, BSZ * NH), 256, 0, stream>>>(Qb, Kb, Vt, O);

  gemm_bt_k<0><<<dim3(2048 / BN, MROWS / BM), 256, 0, stream>>>(O, woT, out, nullptr, MROWS, 2048, 2048, rope);
}

// Round 2
// 595.798 us; speedup vs baseline: 1.1218x; 1.1218x over previous
//
#include <hip/hip_runtime.h>

#define EMB 2048
#define NH 16
#define NKV 4
#define HD 128
#define SLEN 2048
#define BSZ 2
#define MROWS (BSZ * SLEN) // 4096

typedef __attribute__((ext_vector_type(8))) short bf16x8;
typedef __attribute__((ext_vector_type(4))) float f32x4;
typedef __attribute__((ext_vector_type(2))) float f32x2;
typedef __attribute__((ext_vector_type(4))) short s16x4;

__device__ __forceinline__ short f2bf(float f) {
  union { float f; unsigned u; } v; v.f = f;
  unsigned r = (v.u + 0x7fffu + ((v.u >> 16) & 1u)) >> 16;
  return (short)r;
}

// ---------------- RoPE cos/sin table: [SLEN][64] ----------------
__global__ void rope_tab_k(f32x2* __restrict__ tab) {
  int i = blockIdx.x * blockDim.x + threadIdx.x;
  if (i >= SLEN * 64) return;
  int s = i >> 6, j = i & 63;
  float freq = exp2f(-(float)j * (13.287712379549449f / 64.0f));
  float ang = (float)s * freq;
  float sv, cv;
  sincosf(ang, &sv, &cv);
  f32x2 cs; cs[0] = cv; cs[1] = sv;
  tab[i] = cs;
}

// ---------------- fp32 -> bf16 cast (vectorized) ----------------
__global__ void cast_bf16_k(const float* __restrict__ in, short* __restrict__ outp, int n) {
  int i = (blockIdx.x * blockDim.x + threadIdx.x) * 4;
  if (i >= n) return;
  f32x4 v = *(const f32x4*)(in + i);
  s16x4 r;
#pragma unroll
  for (int k = 0; k < 4; ++k) r[k] = f2bf(v[k]);
  *(s16x4*)(outp + i) = r;
}

// ---------------- transpose + cast: in (R,C) fp32 -> out (C,R) bf16 ----------------
__global__ void transpose_cast_k(const float* __restrict__ in, short* __restrict__ outp,
                                 int R, int C) {
  __shared__ float t[32][33];
  int c0 = blockIdx.x * 32, r0 = blockIdx.y * 32;
  int tx = threadIdx.x, ty = threadIdx.y; // 32 x 8
#pragma unroll
  for (int i = 0; i < 4; ++i)
    t[ty + i * 8][tx] = in[(size_t)(r0 + ty + i * 8) * C + (c0 + tx)];
  __syncthreads();
#pragma unroll
  for (int i = 0; i < 4; ++i)
    outp[(size_t)(c0 + ty + i * 8) * R + (r0 + tx)] = f2bf(t[tx][ty + i * 8]);
}

// ---------------- GEMM: C(M,N) = A(M,K) * Bt(N,K)^T, bf16 MFMA ----------------
#define BM 128
#define BN 128
#define BK 32

#define GLL16(g, l)                                                        \
  __builtin_amdgcn_global_load_lds(                                        \
      (const __attribute__((address_space(1))) void*)(g),                  \
      (__attribute__((address_space(3))) void*)(l), 16, 0, 0)

// EPI: 0 = fp32 store to Cf (row-major M x N)
//      1 = RoPE + store Q bf16 as [B][NH][S][HD]
//      2 = RoPE + store K bf16 as [B][NKV][S][HD]
//      3 = store V bf16 transposed as [B][NKV][HD][S]
template <int EPI>
__global__ __launch_bounds__(256, 2) void gemm_bt_k(
    const short* __restrict__ A, const short* __restrict__ Bt,
    float* __restrict__ Cf, short* __restrict__ Cb,
    int M, int N, int K, const f32x2* __restrict__ rope) {
  __shared__ short lA[2][BM * BK];
  __shared__ short lB[2][BN * BK];
  int tid = threadIdx.x;
  int lane = tid & 63, wid = tid >> 6;
  int m0 = blockIdx.y * BM, n0 = blockIdx.x * BN;
  int wr = (wid >> 1) * 64, wc = (wid & 1) * 64;
  int l16 = lane & 15, lk = (lane >> 4) * 8;
  (void)M;

  auto stage = [&](int buf, int k0) {
    const short* ga = A + (size_t)m0 * K + k0;
    const short* gb = Bt + (size_t)n0 * K + k0;
#pragma unroll
    for (int i = 0; i < 2; ++i) {
      int cidx = i * 256 + tid;
      int row = cidx >> 2, c8 = (cidx & 3) << 3;
      GLL16(ga + (size_t)row * K + c8, &lA[buf][(size_t)(i * 256 + (tid & 192)) * 8]);
      GLL16(gb + (size_t)row * K + c8, &lB[buf][(size_t)(i * 256 + (tid & 192)) * 8]);
    }
  };

  f32x4 acc[4][4] = {};
  stage(0, 0);
  asm volatile("s_waitcnt vmcnt(0)" ::: "memory");
  __syncthreads();
  int nk = K / BK;
  for (int t = 0; t < nk; ++t) {
    int buf = t & 1;
    if (t + 1 < nk) stage(buf ^ 1, (t + 1) * BK);
    bf16x8 af[4], bfv[4];
#pragma unroll
    for (int m = 0; m < 4; ++m)
      af[m] = *(const bf16x8*)&lA[buf][(wr + m * 16 + l16) * BK + lk];
#pragma unroll
    for (int n = 0; n < 4; ++n)
      bfv[n] = *(const bf16x8*)&lB[buf][(wc + n * 16 + l16) * BK + lk];
#pragma unroll
    for (int m = 0; m < 4; ++m)
#pragma unroll
      for (int n = 0; n < 4; ++n)
        acc[m][n] = __builtin_amdgcn_mfma_f32_16x16x32_bf16(af[m], bfv[n], acc[m][n], 0, 0, 0);
    asm volatile("s_waitcnt vmcnt(0)" ::: "memory");
    __syncthreads();
  }

  // epilogue: C/D layout col = lane&15, row = (lane>>4)*4 + reg
#pragma unroll
  for (int m = 0; m < 4; ++m) {
#pragma unroll
    for (int n = 0; n < 4; ++n) {
#pragma unroll
      for (int j = 0; j < 4; ++j) {
        int gm = m0 + wr + m * 16 + (lane >> 4) * 4 + j;
        int gc = n0 + wc + n * 16 + l16;
        float v = acc[m][n][j];
        if constexpr (EPI == 0) {
          Cf[(size_t)gm * N + gc] = v;
        } else if constexpr (EPI == 1 || EPI == 2) {
          float p = __shfl_xor(v, 1); // partner column (d^1), same row
          int pos = gm & (SLEN - 1), bb = gm >> 11;
          int head = gc >> 7, d = gc & 127, j2 = d >> 1;
          f32x2 cs = rope[pos * 64 + j2];
          float ov; int od;
          if ((d & 1) == 0) { ov = v * cs[0] - p * cs[1]; od = j2; }
          else              { ov = p * cs[1] + v * cs[0]; od = j2 + 64; }
          const int nh = (EPI == 1) ? NH : NKV;
          Cb[((size_t)(bb * nh + head) * SLEN + pos) * HD + od] = f2bf(ov);
        } else { // EPI == 3: V transposed per (b,kv): [HD][S]
          int pos = gm & (SLEN - 1), bb = gm >> 11;
          int head = gc >> 7, d = gc & 127;
          Cb[((size_t)(bb * NKV + head) * HD + d) * SLEN + pos] = f2bf(v);
        }
      }
    }
  }
}

// ---------------- flash attention (causal, GQA kv = h % 4) ----------------
// 2 waves/block, 16 q-rows per wave, KVBLK=64, deferred sum-reduce,
// XOR-swizzled per-wave P tile (16 rows x 128B).
__global__ __launch_bounds__(128, 2) void flash_k(
    const short* __restrict__ Qb, const short* __restrict__ Kb,
    const short* __restrict__ Vt, short* __restrict__ O) {
  int tid = threadIdx.x, lane = tid & 63, wid = tid >> 6;
  int bh = blockIdx.y;
  int b = bh >> 4, h = bh & 15, kv = h & 3; // jnp.tile => h % NKV
  int l16 = lane & 15, lk4 = lane >> 4;
  int qbw = blockIdx.x * 32 + wid * 16; // this wave's q-row base

  const short* qptr = Qb + (size_t)(b * NH + h) * SLEN * HD;
  const short* kptr = Kb + (size_t)(b * NKV + kv) * SLEN * HD;
  const short* vptr = Vt + (size_t)(b * NKV + kv) * HD * SLEN;

  bf16x8 aq[4];
#pragma unroll
  for (int c = 0; c < 4; ++c)
    aq[c] = *(const bf16x8*)(qptr + (size_t)(qbw + l16) * HD + c * 32 + lk4 * 8);

  f32x4 o[8] = {};
  float ninf = -__builtin_inff();
  float mrow[4] = { ninf, ninf, ninf, ninf };
  float lsum[4] = {};

  __shared__ short Plds[2][16][64]; // per-wave 16 rows x 128B
  char* myP = (char*)&Plds[wid][0][0];

  // scores scaled into exp2 domain: x = s * (1/sqrt(128) * log2(e))
  const float SCL2E = 0.08838834764831845f * 1.4426950408889634f;

  int kend = qbw + 16;
  for (int k0 = 0; k0 < kend; k0 += 64) {
    // ---- QK^T over 64 keys ----
    f32x4 s[4] = {};
#pragma unroll
    for (int t = 0; t < 4; ++t) {
#pragma unroll
      for (int c = 0; c < 4; ++c) {
        bf16x8 bk = *(const bf16x8*)(kptr + (size_t)(k0 + t * 16 + l16) * HD + c * 32 + lk4 * 8);
        s[t] = __builtin_amdgcn_mfma_f32_16x16x32_bf16(aq[c], bk, s[t], 0, 0, 0);
      }
    }
    // ---- online softmax (max-reduce only; sum deferred to per-lane partials) ----
#pragma unroll
    for (int j = 0; j < 4; ++j) {
      int q = qbw + lk4 * 4 + j;
      int prow = lk4 * 4 + j;
      float x[4];
#pragma unroll
      for (int t = 0; t < 4; ++t) {
        x[t] = s[t][j] * SCL2E;
        if (k0 + t * 16 + l16 > q) x[t] = -3.0e38f;
      }
      float mm = fmaxf(fmaxf(x[0], x[1]), fmaxf(x[2], x[3]));
      mm = fmaxf(mm, __shfl_xor(mm, 1));
      mm = fmaxf(mm, __shfl_xor(mm, 2));
      mm = fmaxf(mm, __shfl_xor(mm, 4));
      mm = fmaxf(mm, __shfl_xor(mm, 8));
      float mn = fmaxf(mrow[j], mm);
      float f = exp2f(mrow[j] - mn);
      mrow[j] = mn;
      lsum[j] *= f;
#pragma unroll
      for (int dt = 0; dt < 8; ++dt) o[dt][j] *= f;
#pragma unroll
      for (int t = 0; t < 4; ++t) {
        float p = exp2f(x[t] - mn);
        lsum[j] += p;
        int boff = (prow * 128 + (t * 16 + l16) * 2) ^ ((prow & 7) << 4);
        *(short*)(myP + boff) = f2bf(p);
      }
    }
    asm volatile("s_waitcnt lgkmcnt(0)" ::: "memory");
    __builtin_amdgcn_sched_barrier(0);
    // ---- PV: o += P(16x64) * V^T tiles ----
#pragma unroll
    for (int hh = 0; hh < 2; ++hh) {
      int boff = (l16 * 128 + hh * 64 + lk4 * 16) ^ ((l16 & 7) << 4);
      bf16x8 pa = *(const bf16x8*)(myP + boff);
#pragma unroll
      for (int dt = 0; dt < 8; ++dt) {
        bf16x8 bv = *(const bf16x8*)(vptr + (size_t)(dt * 16 + l16) * SLEN + k0 + hh * 32 + lk4 * 8);
        o[dt] = __builtin_amdgcn_mfma_f32_16x16x32_bf16(pa, bv, o[dt], 0, 0, 0);
      }
    }
  }
  // ---- finalize: cross-lane sum of deferred partials, normalize, store ----
#pragma unroll
  for (int j = 0; j < 4; ++j) {
    float l = lsum[j];
    l += __shfl_xor(l, 1);
    l += __shfl_xor(l, 2);
    l += __shfl_xor(l, 4);
    l += __shfl_xor(l, 8);
    float inv = 1.0f / l;
    int q = qbw + lk4 * 4 + j;
    size_t ro = ((size_t)(b * SLEN + q)) * (NH * HD) + h * HD;
#pragma unroll
    for (int dt = 0; dt < 8; ++dt)
      O[ro + dt * 16 + l16] = f2bf(o[dt][j] * inv);
  }
}

extern "C" void kernel_launch(void* const* d_in, const int* in_sizes, int n_in,
                              void* d_out, int out_size, void* d_ws, size_t ws_size,
                              hipStream_t stream) {
  const float* x  = (const float*)d_in[0];
  const float* wq = (const float*)d_in[1];
  const float* wk = (const float*)d_in[2];
  const float* wv = (const float*)d_in[3];
  const float* wo = (const float*)d_in[4];
  float* out = (float*)d_out;
  char* ws = (char*)d_ws;
  (void)in_sizes; (void)n_in; (void)out_size; (void)ws_size;

  const size_t MB = 1024 * 1024;
  f32x2* rope = (f32x2*)(ws);            // 1 MB
  short* xb  = (short*)(ws + 1 * MB);    // 16 MB (reused as O)
  short* wqT = (short*)(ws + 17 * MB);   // 8 MB
  short* wkT = (short*)(ws + 25 * MB);   // 2 MB
  short* wvT = (short*)(ws + 27 * MB);   // 2 MB
  short* woT = (short*)(ws + 29 * MB);   // 8 MB
  short* Qb  = (short*)(ws + 37 * MB);   // 16 MB
  short* Kb  = (short*)(ws + 53 * MB);   // 4 MB
  short* Vt  = (short*)(ws + 57 * MB);   // 4 MB
  short* O   = xb;                       // alias: xb dead after V GEMM

  rope_tab_k<<<(SLEN * 64 + 255) / 256, 256, 0, stream>>>(rope);
  cast_bf16_k<<<(MROWS * EMB / 4 + 255) / 256, 256, 0, stream>>>(x, xb, MROWS * EMB);

  dim3 tb(32, 8);
  transpose_cast_k<<<dim3(2048 / 32, 2048 / 32), tb, 0, stream>>>(wq, wqT, 2048, 2048);
  transpose_cast_k<<<dim3(512 / 32, 2048 / 32), tb, 0, stream>>>(wk, wkT, 2048, 512);
  transpose_cast_k<<<dim3(512 / 32, 2048 / 32), tb, 0, stream>>>(wv, wvT, 2048, 512);
  transpose_cast_k<<<dim3(2048 / 32, 2048 / 32), tb, 0, stream>>>(wo, woT, 2048, 2048);

  gemm_bt_k<1><<<dim3(2048 / BN, MROWS / BM), 256, 0, stream>>>(xb, wqT, nullptr, Qb, MROWS, 2048, 2048, rope);
  gemm_bt_k<2><<<dim3(512 / BN, MROWS / BM), 256, 0, stream>>>(xb, wkT, nullptr, Kb, MROWS, 512, 2048, rope);
  gemm_bt_k<3><<<dim3(512 / BN, MROWS / BM), 256, 0, stream>>>(xb, wvT, nullptr, Vt, MROWS, 512, 2048, rope);

  flash_k<<<dim3(SLEN / 32, BSZ * NH), 128, 0, stream>>>(Qb, Kb, Vt, O);

  gemm_bt_k<0><<<dim3(2048 / BN, MROWS / BM), 256, 0, stream>>>(O, woT, out, nullptr, MROWS, 2048, 2048, rope);
}

// Round 4
// 595.389 us; speedup vs baseline: 1.1226x; 1.0007x over previous
//
#include <hip/hip_runtime.h>

#define EMB 2048
#define NH 16
#define NKV 4
#define HD 128
#define SLEN 2048
#define BSZ 2
#define MROWS (BSZ * SLEN) // 4096

typedef __attribute__((ext_vector_type(8))) short bf16x8;
typedef __attribute__((ext_vector_type(4))) float f32x4;
typedef __attribute__((ext_vector_type(2))) float f32x2;
typedef __attribute__((ext_vector_type(4))) short s16x4;

__device__ __forceinline__ short f2bf(float f) {
  union { float f; unsigned u; } v; v.f = f;
  unsigned r = (v.u + 0x7fffu + ((v.u >> 16) & 1u)) >> 16;
  return (short)r;
}

// ---------------- RoPE cos/sin table: [SLEN][64] ----------------
__global__ void rope_tab_k(f32x2* __restrict__ tab) {
  int i = blockIdx.x * blockDim.x + threadIdx.x;
  if (i >= SLEN * 64) return;
  int s = i >> 6, j = i & 63;
  float freq = exp2f(-(float)j * (13.287712379549449f / 64.0f));
  float ang = (float)s * freq;
  float sv, cv;
  sincosf(ang, &sv, &cv);
  f32x2 cs; cs[0] = cv; cs[1] = sv;
  tab[i] = cs;
}

// ---------------- fp32 -> bf16 cast (vectorized) ----------------
__global__ void cast_bf16_k(const float* __restrict__ in, short* __restrict__ outp, int n) {
  int i = (blockIdx.x * blockDim.x + threadIdx.x) * 4;
  if (i >= n) return;
  f32x4 v = *(const f32x4*)(in + i);
  s16x4 r;
#pragma unroll
  for (int k = 0; k < 4; ++k) r[k] = f2bf(v[k]);
  *(s16x4*)(outp + i) = r;
}

// ---------------- transpose + cast: in (R,C) fp32 -> out (C,R) bf16 ----------------
__global__ void transpose_cast_k(const float* __restrict__ in, short* __restrict__ outp,
                                 int R, int C) {
  __shared__ float t[32][33];
  int c0 = blockIdx.x * 32, r0 = blockIdx.y * 32;
  int tx = threadIdx.x, ty = threadIdx.y; // 32 x 8
#pragma unroll
  for (int i = 0; i < 4; ++i)
    t[ty + i * 8][tx] = in[(size_t)(r0 + ty + i * 8) * C + (c0 + tx)];
  __syncthreads();
#pragma unroll
  for (int i = 0; i < 4; ++i)
    outp[(size_t)(c0 + ty + i * 8) * R + (r0 + tx)] = f2bf(t[tx][ty + i * 8]);
}

// ---------------- GEMM: C(M,N) = A(M,K) * Bt(N,K)^T, bf16 MFMA ----------------
#define BM 128
#define BN 128
#define BK 32

#define GLL16(g, l)                                                        \
  __builtin_amdgcn_global_load_lds(                                        \
      (const __attribute__((address_space(1))) void*)(g),                  \
      (__attribute__((address_space(3))) void*)(l), 16, 0, 0)

// EPI: 0 = fp32 store to Cf (row-major M x N)
//      1 = RoPE + pre-scale by 1/sqrt(128)*log2(e) + store Q bf16 [B][NH][S][HD]
//      2 = RoPE + store K bf16 as [B][NKV][S][HD]
//      3 = store V bf16 transposed as [B][NKV][HD][S]
template <int EPI>
__global__ __launch_bounds__(256, 2) void gemm_bt_k(
    const short* __restrict__ A, const short* __restrict__ Bt,
    float* __restrict__ Cf, short* __restrict__ Cb,
    int M, int N, int K, const f32x2* __restrict__ rope) {
  __shared__ short lA[2][BM * BK];
  __shared__ short lB[2][BN * BK];
  int tid = threadIdx.x;
  int lane = tid & 63, wid = tid >> 6;
  int m0 = blockIdx.y * BM, n0 = blockIdx.x * BN;
  int wr = (wid >> 1) * 64, wc = (wid & 1) * 64;
  int l16 = lane & 15, lk = (lane >> 4) * 8;
  (void)M;

  auto stage = [&](int buf, int k0) {
    const short* ga = A + (size_t)m0 * K + k0;
    const short* gb = Bt + (size_t)n0 * K + k0;
#pragma unroll
    for (int i = 0; i < 2; ++i) {
      int cidx = i * 256 + tid;
      int row = cidx >> 2, c8 = (cidx & 3) << 3;
      GLL16(ga + (size_t)row * K + c8, &lA[buf][(size_t)(i * 256 + (tid & 192)) * 8]);
      GLL16(gb + (size_t)row * K + c8, &lB[buf][(size_t)(i * 256 + (tid & 192)) * 8]);
    }
  };

  f32x4 acc[4][4] = {};
  stage(0, 0);
  asm volatile("s_waitcnt vmcnt(0)" ::: "memory");
  __syncthreads();
  int nk = K / BK;
  for (int t = 0; t < nk; ++t) {
    int buf = t & 1;
    if (t + 1 < nk) stage(buf ^ 1, (t + 1) * BK);
    bf16x8 af[4], bfv[4];
#pragma unroll
    for (int m = 0; m < 4; ++m)
      af[m] = *(const bf16x8*)&lA[buf][(wr + m * 16 + l16) * BK + lk];
#pragma unroll
    for (int n = 0; n < 4; ++n)
      bfv[n] = *(const bf16x8*)&lB[buf][(wc + n * 16 + l16) * BK + lk];
#pragma unroll
    for (int m = 0; m < 4; ++m)
#pragma unroll
      for (int n = 0; n < 4; ++n)
        acc[m][n] = __builtin_amdgcn_mfma_f32_16x16x32_bf16(af[m], bfv[n], acc[m][n], 0, 0, 0);
    asm volatile("s_waitcnt vmcnt(0)" ::: "memory");
    __syncthreads();
  }

  const float SCL2E = 0.08838834764831845f * 1.4426950408889634f;
  // epilogue: C/D layout col = lane&15, row = (lane>>4)*4 + reg
#pragma unroll
  for (int m = 0; m < 4; ++m) {
#pragma unroll
    for (int n = 0; n < 4; ++n) {
#pragma unroll
      for (int j = 0; j < 4; ++j) {
        int gm = m0 + wr + m * 16 + (lane >> 4) * 4 + j;
        int gc = n0 + wc + n * 16 + l16;
        float v = acc[m][n][j];
        if constexpr (EPI == 0) {
          Cf[(size_t)gm * N + gc] = v;
        } else if constexpr (EPI == 1 || EPI == 2) {
          float p = __shfl_xor(v, 1); // partner column (d^1), same row
          int pos = gm & (SLEN - 1), bb = gm >> 11;
          int head = gc >> 7, d = gc & 127, j2 = d >> 1;
          f32x2 cs = rope[pos * 64 + j2];
          float ov; int od;
          if ((d & 1) == 0) { ov = v * cs[0] - p * cs[1]; od = j2; }
          else              { ov = p * cs[1] + v * cs[0]; od = j2 + 64; }
          if constexpr (EPI == 1) ov *= SCL2E; // fold attn scale*log2e into Q
          const int nh = (EPI == 1) ? NH : NKV;
          Cb[((size_t)(bb * nh + head) * SLEN + pos) * HD + od] = f2bf(ov);
        } else { // EPI == 3: V transposed per (b,kv): [HD][S]
          int pos = gm & (SLEN - 1), bb = gm >> 11;
          int head = gc >> 7, d = gc & 127;
          Cb[((size_t)(bb * NKV + head) * HD + d) * SLEN + pos] = f2bf(v);
        }
      }
    }
  }
}

// ---------------- flash attention, swapped-operand form ----------------
// 2 waves/block, 16 q-rows/wave (q = qbw + (lane&15)), KVBLK=64.
// QK^T computed as mfma(K,Q) -> lane holds 16 scores of ONE q-row -> in-lane
// softmax (2 shuffles for max, deferred sum). PV computed as mfma(V^T,P) ->
// output q also lane-local. P through LDS: 4x ds_write_b64 + 2x ds_read_b128,
// XOR-swizzled. lgkmcnt(0)+sched_barrier(0) fence between P-write and P-read
// is REQUIRED: write type (ull*) and read type (bf16x8*) don't alias under
// TBAA, so without the fence the compiler hoists the reads (R3 NaN bug).
__global__ __launch_bounds__(128, 3) void flash_k(
    const short* __restrict__ Qb, const short* __restrict__ Kb,
    const short* __restrict__ Vt, short* __restrict__ O) {
  int tid = threadIdx.x, lane = tid & 63, wid = tid >> 6;
  int bh = blockIdx.y;
  int b = bh >> 4, h = bh & 15, kv = h & 3; // jnp.tile => h % NKV
  int l16 = lane & 15, lk4 = lane >> 4;
  int qt = (SLEN / 32 - 1) - blockIdx.x; // heavy tiles first
  int qbw = qt * 32 + wid * 16;

  const short* qptr = Qb + (size_t)(b * NH + h) * SLEN * HD;
  const short* kptr = Kb + (size_t)(b * NKV + kv) * SLEN * HD;
  const short* vptr = Vt + (size_t)(b * NKV + kv) * HD * SLEN;

  bf16x8 aq[4];
#pragma unroll
  for (int c = 0; c < 4; ++c)
    aq[c] = *(const bf16x8*)(qptr + (size_t)(qbw + l16) * HD + c * 32 + lk4 * 8);

  f32x4 o[8] = {};
  float m = -__builtin_inff();
  float lsum = 0.0f;

  __shared__ short Plds[2][16][64]; // per-wave 16 rows x 128B
  char* myP = (char*)&Plds[wid][0][0];
  int swz = (l16 & 7) << 4;

  int kend = qbw + 16;
  for (int k0 = 0; k0 < kend; k0 += 64) {
    // ---- QK^T (swapped): s[t][j] = S[key=k0+t*16+lk4*4+j][q=qbw+l16] ----
    f32x4 s[4] = {};
#pragma unroll
    for (int c = 0; c < 4; ++c) {
#pragma unroll
      for (int t = 0; t < 4; ++t) {
        bf16x8 bk = *(const bf16x8*)(kptr + (size_t)(k0 + t * 16 + l16) * HD + c * 32 + lk4 * 8);
        s[t] = __builtin_amdgcn_mfma_f32_16x16x32_bf16(bk, aq[c], s[t], 0, 0, 0);
      }
    }
    // ---- V loads for first 32 keys (hide L2 latency under softmax) ----
    bf16x8 bv0[8];
#pragma unroll
    for (int dt = 0; dt < 8; ++dt)
      bv0[dt] = *(const bf16x8*)(vptr + (size_t)(dt * 16 + l16) * SLEN + k0 + lk4 * 8);

    // ---- in-lane softmax ----
    float x[16];
#pragma unroll
    for (int t = 0; t < 4; ++t)
#pragma unroll
      for (int j = 0; j < 4; ++j) x[t * 4 + j] = s[t][j];
    if (k0 + 63 > qbw) { // tile touches the causal diagonal
      int kq = k0 + lk4 * 4 - qbw - l16;
#pragma unroll
      for (int t = 0; t < 4; ++t)
#pragma unroll
        for (int j = 0; j < 4; ++j)
          if (kq + t * 16 + j > 0) x[t * 4 + j] = -3.0e38f;
    }
    float a0 = fmaxf(x[0], x[1]), a1 = fmaxf(x[2], x[3]);
    float a2 = fmaxf(x[4], x[5]), a3 = fmaxf(x[6], x[7]);
    float a4 = fmaxf(x[8], x[9]), a5 = fmaxf(x[10], x[11]);
    float a6 = fmaxf(x[12], x[13]), a7 = fmaxf(x[14], x[15]);
    float b0 = fmaxf(fmaxf(a0, a1), fmaxf(a2, a3));
    float b1 = fmaxf(fmaxf(a4, a5), fmaxf(a6, a7));
    float tm = fmaxf(b0, b1);
    tm = fmaxf(tm, __shfl_xor(tm, 16));
    tm = fmaxf(tm, __shfl_xor(tm, 32));
    float mn = fmaxf(m, tm);
    if (!__all(tm <= m + 8.0f)) { // T13 defer-rescale
      float f = __builtin_amdgcn_exp2f(m - mn);
      m = mn;
      lsum *= f;
#pragma unroll
      for (int dt = 0; dt < 8; ++dt) o[dt] *= f;
    }
    float psum = 0.0f;
#pragma unroll
    for (int t = 0; t < 4; ++t) {
      float p0 = __builtin_amdgcn_exp2f(x[t * 4 + 0] - m);
      float p1 = __builtin_amdgcn_exp2f(x[t * 4 + 1] - m);
      float p2 = __builtin_amdgcn_exp2f(x[t * 4 + 2] - m);
      float p3 = __builtin_amdgcn_exp2f(x[t * 4 + 3] - m);
      psum += (p0 + p1) + (p2 + p3);
      unsigned lo, hi;
      asm("v_cvt_pk_bf16_f32 %0, %1, %2" : "=v"(lo) : "v"(p0), "v"(p1));
      asm("v_cvt_pk_bf16_f32 %0, %1, %2" : "=v"(hi) : "v"(p2), "v"(p3));
      unsigned long long dw = ((unsigned long long)hi << 32) | lo;
      *(unsigned long long*)(myP + ((l16 * 128 + t * 32 + lk4 * 8) ^ swz)) = dw;
    }
    lsum += psum;
    // ---- V loads for second 32 keys ----
    bf16x8 bv1[8];
#pragma unroll
    for (int dt = 0; dt < 8; ++dt)
      bv1[dt] = *(const bf16x8*)(vptr + (size_t)(dt * 16 + l16) * SLEN + k0 + 32 + lk4 * 8);
    // ---- ORDERING FENCE: drain ds_writes, pin ds_reads below (rule #18) ----
    asm volatile("s_waitcnt lgkmcnt(0)" ::: "memory");
    __builtin_amdgcn_sched_barrier(0);
    // ---- PV (swapped): o[dt][j] = O[q=qbw+l16][d=dt*16+lk4*4+j] ----
    bf16x8 pa0 = *(const bf16x8*)(myP + ((l16 * 128 + 0 + lk4 * 16) ^ swz));
#pragma unroll
    for (int dt = 0; dt < 8; ++dt)
      o[dt] = __builtin_amdgcn_mfma_f32_16x16x32_bf16(bv0[dt], pa0, o[dt], 0, 0, 0);
    bf16x8 pa1 = *(const bf16x8*)(myP + ((l16 * 128 + 64 + lk4 * 16) ^ swz));
#pragma unroll
    for (int dt = 0; dt < 8; ++dt)
      o[dt] = __builtin_amdgcn_mfma_f32_16x16x32_bf16(bv1[dt], pa1, o[dt], 0, 0, 0);
  }
  // ---- finalize: reduce deferred partial sums across the 4 key-groups ----
  lsum += __shfl_xor(lsum, 16);
  lsum += __shfl_xor(lsum, 32);
  float inv = 1.0f / lsum;
  size_t ro = ((size_t)(b * SLEN + qbw + l16)) * (NH * HD) + h * HD;
#pragma unroll
  for (int dt = 0; dt < 8; ++dt) {
    s16x4 r;
#pragma unroll
    for (int j = 0; j < 4; ++j) r[j] = f2bf(o[dt][j] * inv);
    *(s16x4*)(O + ro + dt * 16 + lk4 * 4) = r;
  }
}

extern "C" void kernel_launch(void* const* d_in, const int* in_sizes, int n_in,
                              void* d_out, int out_size, void* d_ws, size_t ws_size,
                              hipStream_t stream) {
  const float* x  = (const float*)d_in[0];
  const float* wq = (const float*)d_in[1];
  const float* wk = (const float*)d_in[2];
  const float* wv = (const float*)d_in[3];
  const float* wo = (const float*)d_in[4];
  float* out = (float*)d_out;
  char* ws = (char*)d_ws;
  (void)in_sizes; (void)n_in; (void)out_size; (void)ws_size;

  const size_t MB = 1024 * 1024;
  f32x2* rope = (f32x2*)(ws);            // 1 MB
  short* xb  = (short*)(ws + 1 * MB);    // 16 MB (reused as O)
  short* wqT = (short*)(ws + 17 * MB);   // 8 MB
  short* wkT = (short*)(ws + 25 * MB);   // 2 MB
  short* wvT = (short*)(ws + 27 * MB);   // 2 MB
  short* woT = (short*)(ws + 29 * MB);   // 8 MB
  short* Qb  = (short*)(ws + 37 * MB);   // 16 MB
  short* Kb  = (short*)(ws + 53 * MB);   // 4 MB
  short* Vt  = (short*)(ws + 57 * MB);   // 4 MB
  short* O   = xb;                       // alias: xb dead after V GEMM

  rope_tab_k<<<(SLEN * 64 + 255) / 256, 256, 0, stream>>>(rope);
  cast_bf16_k<<<(MROWS * EMB / 4 + 255) / 256, 256, 0, stream>>>(x, xb, MROWS * EMB);

  dim3 tb(32, 8);
  transpose_cast_k<<<dim3(2048 / 32, 2048 / 32), tb, 0, stream>>>(wq, wqT, 2048, 2048);
  transpose_cast_k<<<dim3(512 / 32, 2048 / 32), tb, 0, stream>>>(wk, wkT, 2048, 512);
  transpose_cast_k<<<dim3(512 / 32, 2048 / 32), tb, 0, stream>>>(wv, wvT, 2048, 512);
  transpose_cast_k<<<dim3(2048 / 32, 2048 / 32), tb, 0, stream>>>(wo, woT, 2048, 2048);

  gemm_bt_k<1><<<dim3(2048 / BN, MROWS / BM), 256, 0, stream>>>(xb, wqT, nullptr, Qb, MROWS, 2048, 2048, rope);
  gemm_bt_k<2><<<dim3(512 / BN, MROWS / BM), 256, 0, stream>>>(xb, wkT, nullptr, Kb, MROWS, 512, 2048, rope);
  gemm_bt_k<3><<<dim3(512 / BN, MROWS / BM), 256, 0, stream>>>(xb, wvT, nullptr, Vt, MROWS, 512, 2048, rope);

  flash_k<<<dim3(SLEN / 32, BSZ * NH), 128, 0, stream>>>(Qb, Kb, Vt, O);

  gemm_bt_k<0><<<dim3(2048 / BN, MROWS / BM), 256, 0, stream>>>(O, woT, out, nullptr, MROWS, 2048, 2048, rope);
}

// Round 5
// 302.338 us; speedup vs baseline: 2.2107x; 1.9693x over previous
//
#include <hip/hip_runtime.h>

#define EMB 2048
#define NH 16
#define NKV 4
#define HD 128
#define SLEN 2048
#define BSZ 2
#define MROWS (BSZ * SLEN) // 4096

typedef __attribute__((ext_vector_type(8))) short bf16x8;
typedef __attribute__((ext_vector_type(4))) float f32x4;
typedef __attribute__((ext_vector_type(2))) float f32x2;
typedef __attribute__((ext_vector_type(4))) short s16x4;

__device__ __forceinline__ short f2bf(float f) {
  union { float f; unsigned u; } v; v.f = f;
  unsigned r = (v.u + 0x7fffu + ((v.u >> 16) & 1u)) >> 16;
  return (short)r;
}

// ---------------- RoPE cos/sin table: [SLEN][64] ----------------
__global__ void rope_tab_k(f32x2* __restrict__ tab) {
  int i = blockIdx.x * blockDim.x + threadIdx.x;
  if (i >= SLEN * 64) return;
  int s = i >> 6, j = i & 63;
  float freq = exp2f(-(float)j * (13.287712379549449f / 64.0f));
  float ang = (float)s * freq;
  float sv, cv;
  sincosf(ang, &sv, &cv);
  f32x2 cs; cs[0] = cv; cs[1] = sv;
  tab[i] = cs;
}

// ---------------- fp32 -> bf16 cast (vectorized) ----------------
__global__ void cast_bf16_k(const float* __restrict__ in, short* __restrict__ outp, int n) {
  int i = (blockIdx.x * blockDim.x + threadIdx.x) * 4;
  if (i >= n) return;
  f32x4 v = *(const f32x4*)(in + i);
  s16x4 r;
#pragma unroll
  for (int k = 0; k < 4; ++k) r[k] = f2bf(v[k]);
  *(s16x4*)(outp + i) = r;
}

// ---------------- transpose + cast: in (R,C) fp32 -> out (C,R) bf16 ----------------
__global__ void transpose_cast_k(const float* __restrict__ in, short* __restrict__ outp,
                                 int R, int C) {
  __shared__ float t[32][33];
  int c0 = blockIdx.x * 32, r0 = blockIdx.y * 32;
  int tx = threadIdx.x, ty = threadIdx.y; // 32 x 8
#pragma unroll
  for (int i = 0; i < 4; ++i)
    t[ty + i * 8][tx] = in[(size_t)(r0 + ty + i * 8) * C + (c0 + tx)];
  __syncthreads();
#pragma unroll
  for (int i = 0; i < 4; ++i)
    outp[(size_t)(c0 + ty + i * 8) * R + (r0 + tx)] = f2bf(t[tx][ty + i * 8]);
}

// ---------------- GEMM: C(M,N) = A(M,K) * Bt(N,K)^T, bf16 MFMA ----------------
#define BM 128
#define BN 128
#define BK 32

#define GLL16(g, l)                                                        \
  __builtin_amdgcn_global_load_lds(                                        \
      (const __attribute__((address_space(1))) void*)(g),                  \
      (__attribute__((address_space(3))) void*)(l), 16, 0, 0)

// EPI: 0 = fp32 store to Cf (row-major M x N)
//      1 = RoPE + pre-scale by 1/sqrt(128)*log2(e) + store Q bf16 [B][NH][S][HD]
//      2 = RoPE + store K bf16 as [B][NKV][S][HD]
//      3 = store V bf16 transposed as [B][NKV][HD][S]
template <int EPI>
__global__ __launch_bounds__(256, 2) void gemm_bt_k(
    const short* __restrict__ A, const short* __restrict__ Bt,
    float* __restrict__ Cf, short* __restrict__ Cb,
    int M, int N, int K, const f32x2* __restrict__ rope) {
  __shared__ short lA[2][BM * BK];
  __shared__ short lB[2][BN * BK];
  int tid = threadIdx.x;
  int lane = tid & 63, wid = tid >> 6;
  int m0 = blockIdx.y * BM, n0 = blockIdx.x * BN;
  int wr = (wid >> 1) * 64, wc = (wid & 1) * 64;
  int l16 = lane & 15, lk = (lane >> 4) * 8;
  (void)M;

  auto stage = [&](int buf, int k0) {
    const short* ga = A + (size_t)m0 * K + k0;
    const short* gb = Bt + (size_t)n0 * K + k0;
#pragma unroll
    for (int i = 0; i < 2; ++i) {
      int cidx = i * 256 + tid;
      int row = cidx >> 2, c8 = (cidx & 3) << 3;
      GLL16(ga + (size_t)row * K + c8, &lA[buf][(size_t)(i * 256 + (tid & 192)) * 8]);
      GLL16(gb + (size_t)row * K + c8, &lB[buf][(size_t)(i * 256 + (tid & 192)) * 8]);
    }
  };

  f32x4 acc[4][4] = {};
  stage(0, 0);
  asm volatile("s_waitcnt vmcnt(0)" ::: "memory");
  __syncthreads();
  int nk = K / BK;
  for (int t = 0; t < nk; ++t) {
    int buf = t & 1;
    if (t + 1 < nk) stage(buf ^ 1, (t + 1) * BK);
    bf16x8 af[4], bfv[4];
#pragma unroll
    for (int m = 0; m < 4; ++m)
      af[m] = *(const bf16x8*)&lA[buf][(wr + m * 16 + l16) * BK + lk];
#pragma unroll
    for (int n = 0; n < 4; ++n)
      bfv[n] = *(const bf16x8*)&lB[buf][(wc + n * 16 + l16) * BK + lk];
#pragma unroll
    for (int m = 0; m < 4; ++m)
#pragma unroll
      for (int n = 0; n < 4; ++n)
        acc[m][n] = __builtin_amdgcn_mfma_f32_16x16x32_bf16(af[m], bfv[n], acc[m][n], 0, 0, 0);
    asm volatile("s_waitcnt vmcnt(0)" ::: "memory");
    __syncthreads();
  }

  const float SCL2E = 0.08838834764831845f * 1.4426950408889634f;
  // epilogue: C/D layout col = lane&15, row = (lane>>4)*4 + reg
#pragma unroll
  for (int m = 0; m < 4; ++m) {
#pragma unroll
    for (int n = 0; n < 4; ++n) {
#pragma unroll
      for (int j = 0; j < 4; ++j) {
        int gm = m0 + wr + m * 16 + (lane >> 4) * 4 + j;
        int gc = n0 + wc + n * 16 + l16;
        float v = acc[m][n][j];
        if constexpr (EPI == 0) {
          Cf[(size_t)gm * N + gc] = v;
        } else if constexpr (EPI == 1 || EPI == 2) {
          float p = __shfl_xor(v, 1); // partner column (d^1), same row
          int pos = gm & (SLEN - 1), bb = gm >> 11;
          int head = gc >> 7, d = gc & 127, j2 = d >> 1;
          f32x2 cs = rope[pos * 64 + j2];
          float ov; int od;
          if ((d & 1) == 0) { ov = v * cs[0] - p * cs[1]; od = j2; }
          else              { ov = p * cs[1] + v * cs[0]; od = j2 + 64; }
          if constexpr (EPI == 1) ov *= SCL2E; // fold attn scale*log2e into Q
          const int nh = (EPI == 1) ? NH : NKV;
          Cb[((size_t)(bb * nh + head) * SLEN + pos) * HD + od] = f2bf(ov);
        } else { // EPI == 3: V transposed per (b,kv): [HD][S]
          int pos = gm & (SLEN - 1), bb = gm >> 11;
          int head = gc >> 7, d = gc & 127;
          Cb[((size_t)(bb * NKV + head) * HD + d) * SLEN + pos] = f2bf(v);
        }
      }
    }
  }
}

// ---------------- flash attention, LDS-cooperative swapped-operand form ----
// 8 waves/block (512 thr), QBLK=128 (16 q-rows/wave), KVBLK=64.
// K and V tiles double-buffered in LDS via global_load_lds (linear dest,
// inverse-swizzled global source, XOR-swizzled ds_read: rule #21).
// QK^T swapped (mfma(K,Q)) -> in-lane softmax; PV swapped -> lane-local q.
// P through per-wave LDS with lgkmcnt fence (R3 NaN lesson, rule #18).
__global__ __launch_bounds__(512, 3) void flash_k(
    const short* __restrict__ Qb, const short* __restrict__ Kb,
    const short* __restrict__ Vt, short* __restrict__ O) {
  __shared__ short lK[2][64 * 128];   // 64 key rows x 256B
  __shared__ short lV[2][128 * 64];   // 128 dim rows x 128B
  __shared__ short Plds[8][16][64];   // per-wave P: 16 rows x 128B

  int tid = threadIdx.x, lane = tid & 63, wid = tid >> 6;
  int bh = blockIdx.y;
  int b = bh >> 4, h = bh & 15, kv = h & 3; // jnp.tile => h % NKV
  int l16 = lane & 15, lk4 = lane >> 4;
  int qt = (SLEN / 128 - 1) - blockIdx.x; // heavy tiles first
  int qbw = qt * 128 + wid * 16;          // this wave's q-row base

  const short* qptr = Qb + (size_t)(b * NH + h) * SLEN * HD;
  const char* kg = (const char*)(Kb + (size_t)(b * NKV + kv) * SLEN * HD);
  const char* vg = (const char*)(Vt + (size_t)(b * NKV + kv) * HD * SLEN);

  bf16x8 aq[4];
#pragma unroll
  for (int c = 0; c < 4; ++c)
    aq[c] = *(const bf16x8*)(qptr + (size_t)(qbw + l16) * HD + c * 32 + lk4 * 8);

  f32x4 o[8] = {};
  float m = -__builtin_inff();
  float lsum = 0.0f;

  char* myP = (char*)&Plds[wid][0][0];
  int swz = (l16 & 7) << 4;

  // stage one 64-key K tile + V tile into LDS buf.
  // LDS byte X holds global[row][cb ^ ((row&7)<<4)] -> swizzled read hits
  // the logical element; global_load_lds dest is linear (base + lane*16).
  auto stageKV = [&](int buf, int k0) {
#pragma unroll
    for (int r = 0; r < 2; ++r) { // K: 16KB = 2 rounds x 512 thr x 16B
      int X = tid * 16 + r * 8192;
      int row = X >> 8, cb = X & 255;
      GLL16(kg + (size_t)(k0 + row) * 256 + (cb ^ ((row & 7) << 4)),
            (char*)&lK[buf][0] + X);
    }
#pragma unroll
    for (int r = 0; r < 2; ++r) { // V: 16KB
      int X = tid * 16 + r * 8192;
      int row = X >> 7, cb = X & 127;
      GLL16(vg + (size_t)row * (SLEN * 2) + k0 * 2 + (cb ^ ((row & 7) << 4)),
            (char*)&lV[buf][0] + X);
    }
  };

  int ntiles = 2 * (qt + 1); // block kend = (qt+1)*128
  stageKV(0, 0);
  asm volatile("s_waitcnt vmcnt(0)" ::: "memory");
  __syncthreads();

  for (int tt = 0; tt < ntiles; ++tt) {
    int buf = tt & 1;
    int k0 = tt * 64;
    if (tt + 1 < ntiles) stageKV(buf ^ 1, (tt + 1) * 64);

    if (k0 < qbw + 16) { // this wave still has unmasked keys in this tile
      const char* Kbase = (const char*)&lK[buf][0];
      const char* Vbase = (const char*)&lV[buf][0];
      // ---- QK^T (swapped): s[t][j] = S[key=k0+t*16+lk4*4+j][q=qbw+l16] ----
      f32x4 s[4] = {};
#pragma unroll
      for (int c = 0; c < 4; ++c) {
#pragma unroll
        for (int t = 0; t < 4; ++t) {
          bf16x8 bk = *(const bf16x8*)(Kbase + (t * 16 + l16) * 256 + ((c * 64 + lk4 * 16) ^ swz));
          s[t] = __builtin_amdgcn_mfma_f32_16x16x32_bf16(bk, aq[c], s[t], 0, 0, 0);
        }
      }
      // ---- in-lane softmax ----
      float x[16];
#pragma unroll
      for (int t = 0; t < 4; ++t)
#pragma unroll
        for (int j = 0; j < 4; ++j) x[t * 4 + j] = s[t][j];
      if (k0 + 63 > qbw) { // tile touches this wave's causal diagonal
        int kq = k0 + lk4 * 4 - qbw - l16;
#pragma unroll
        for (int t = 0; t < 4; ++t)
#pragma unroll
          for (int j = 0; j < 4; ++j)
            if (kq + t * 16 + j > 0) x[t * 4 + j] = -3.0e38f;
      }
      float a0 = fmaxf(x[0], x[1]), a1 = fmaxf(x[2], x[3]);
      float a2 = fmaxf(x[4], x[5]), a3 = fmaxf(x[6], x[7]);
      float a4 = fmaxf(x[8], x[9]), a5 = fmaxf(x[10], x[11]);
      float a6 = fmaxf(x[12], x[13]), a7 = fmaxf(x[14], x[15]);
      float b0 = fmaxf(fmaxf(a0, a1), fmaxf(a2, a3));
      float b1 = fmaxf(fmaxf(a4, a5), fmaxf(a6, a7));
      float tm = fmaxf(b0, b1);
      tm = fmaxf(tm, __shfl_xor(tm, 16));
      tm = fmaxf(tm, __shfl_xor(tm, 32));
      float mn = fmaxf(m, tm);
      if (!__all(tm <= m + 8.0f)) { // T13 defer-rescale
        float f = __builtin_amdgcn_exp2f(m - mn);
        m = mn;
        lsum *= f;
#pragma unroll
        for (int dt = 0; dt < 8; ++dt) o[dt] *= f;
      }
      float psum = 0.0f;
#pragma unroll
      for (int t = 0; t < 4; ++t) {
        float p0 = __builtin_amdgcn_exp2f(x[t * 4 + 0] - m);
        float p1 = __builtin_amdgcn_exp2f(x[t * 4 + 1] - m);
        float p2 = __builtin_amdgcn_exp2f(x[t * 4 + 2] - m);
        float p3 = __builtin_amdgcn_exp2f(x[t * 4 + 3] - m);
        psum += (p0 + p1) + (p2 + p3);
        unsigned lo, hi;
        asm("v_cvt_pk_bf16_f32 %0, %1, %2" : "=v"(lo) : "v"(p0), "v"(p1));
        asm("v_cvt_pk_bf16_f32 %0, %1, %2" : "=v"(hi) : "v"(p2), "v"(p3));
        unsigned long long dw = ((unsigned long long)hi << 32) | lo;
        *(unsigned long long*)(myP + ((l16 * 128 + t * 32 + lk4 * 8) ^ swz)) = dw;
      }
      lsum += psum;
      // ---- ORDERING FENCE (rule #18): drain P ds_writes, pin reads below --
      asm volatile("s_waitcnt lgkmcnt(0)" ::: "memory");
      __builtin_amdgcn_sched_barrier(0);
      // ---- PV (swapped): o[dt][j] = O[q=qbw+l16][d=dt*16+lk4*4+j] ----
#pragma unroll
      for (int hh = 0; hh < 2; ++hh) {
        bf16x8 pa = *(const bf16x8*)(myP + ((l16 * 128 + hh * 64 + lk4 * 16) ^ swz));
#pragma unroll
        for (int dt = 0; dt < 8; ++dt) {
          bf16x8 bv = *(const bf16x8*)(Vbase + (dt * 16 + l16) * 128 + ((hh * 64 + lk4 * 16) ^ swz));
          o[dt] = __builtin_amdgcn_mfma_f32_16x16x32_bf16(bv, pa, o[dt], 0, 0, 0);
        }
      }
    }
    asm volatile("s_waitcnt vmcnt(0)" ::: "memory");
    __syncthreads();
  }
  // ---- finalize: reduce deferred partial sums across the 4 key-groups ----
  lsum += __shfl_xor(lsum, 16);
  lsum += __shfl_xor(lsum, 32);
  float inv = 1.0f / lsum;
  size_t ro = ((size_t)(b * SLEN + qbw + l16)) * (NH * HD) + h * HD;
#pragma unroll
  for (int dt = 0; dt < 8; ++dt) {
    s16x4 r;
#pragma unroll
    for (int j = 0; j < 4; ++j) r[j] = f2bf(o[dt][j] * inv);
    *(s16x4*)(O + ro + dt * 16 + lk4 * 4) = r;
  }
}

extern "C" void kernel_launch(void* const* d_in, const int* in_sizes, int n_in,
                              void* d_out, int out_size, void* d_ws, size_t ws_size,
                              hipStream_t stream) {
  const float* x  = (const float*)d_in[0];
  const float* wq = (const float*)d_in[1];
  const float* wk = (const float*)d_in[2];
  const float* wv = (const float*)d_in[3];
  const float* wo = (const float*)d_in[4];
  float* out = (float*)d_out;
  char* ws = (char*)d_ws;
  (void)in_sizes; (void)n_in; (void)out_size; (void)ws_size;

  const size_t MB = 1024 * 1024;
  f32x2* rope = (f32x2*)(ws);            // 1 MB
  short* xb  = (short*)(ws + 1 * MB);    // 16 MB (reused as O)
  short* wqT = (short*)(ws + 17 * MB);   // 8 MB
  short* wkT = (short*)(ws + 25 * MB);   // 2 MB
  short* wvT = (short*)(ws + 27 * MB);   // 2 MB
  short* woT = (short*)(ws + 29 * MB);   // 8 MB
  short* Qb  = (short*)(ws + 37 * MB);   // 16 MB
  short* Kb  = (short*)(ws + 53 * MB);   // 4 MB
  short* Vt  = (short*)(ws + 57 * MB);   // 4 MB
  short* O   = xb;                       // alias: xb dead after V GEMM

  rope_tab_k<<<(SLEN * 64 + 255) / 256, 256, 0, stream>>>(rope);
  cast_bf16_k<<<(MROWS * EMB / 4 + 255) / 256, 256, 0, stream>>>(x, xb, MROWS * EMB);

  dim3 tb(32, 8);
  transpose_cast_k<<<dim3(2048 / 32, 2048 / 32), tb, 0, stream>>>(wq, wqT, 2048, 2048);
  transpose_cast_k<<<dim3(512 / 32, 2048 / 32), tb, 0, stream>>>(wk, wkT, 2048, 512);
  transpose_cast_k<<<dim3(512 / 32, 2048 / 32), tb, 0, stream>>>(wv, wvT, 2048, 512);
  transpose_cast_k<<<dim3(2048 / 32, 2048 / 32), tb, 0, stream>>>(wo, woT, 2048, 2048);

  gemm_bt_k<1><<<dim3(2048 / BN, MROWS / BM), 256, 0, stream>>>(xb, wqT, nullptr, Qb, MROWS, 2048, 2048, rope);
  gemm_bt_k<2><<<dim3(512 / BN, MROWS / BM), 256, 0, stream>>>(xb, wkT, nullptr, Kb, MROWS, 512, 2048, rope);
  gemm_bt_k<3><<<dim3(512 / BN, MROWS / BM), 256, 0, stream>>>(xb, wvT, nullptr, Vt, MROWS, 512, 2048, rope);

  flash_k<<<dim3(SLEN / 128, BSZ * NH), 512, 0, stream>>>(Qb, Kb, Vt, O);

  gemm_bt_k<0><<<dim3(2048 / BN, MROWS / BM), 256, 0, stream>>>(O, woT, out, nullptr, MROWS, 2048, 2048, rope);
}

// Round 6
// 237.534 us; speedup vs baseline: 2.8138x; 1.2728x over previous
//
#include <hip/hip_runtime.h>

#define EMB 2048
#define NH 16
#define NKV 4
#define HD 128
#define SLEN 2048
#define BSZ 2
#define MROWS (BSZ * SLEN) // 4096

// element offsets within the fused QKV output buffer
#define QOFF (BSZ * NH * SLEN * HD)   // 8388608
#define KOFF (BSZ * NKV * SLEN * HD)  // 2097152

typedef __attribute__((ext_vector_type(8))) short bf16x8;
typedef __attribute__((ext_vector_type(4))) float f32x4;
typedef __attribute__((ext_vector_type(2))) float f32x2;
typedef __attribute__((ext_vector_type(4))) short s16x4;

__device__ __forceinline__ short f2bf(float f) {
  union { float f; unsigned u; } v; v.f = f;
  unsigned r = (v.u + 0x7fffu + ((v.u >> 16) & 1u)) >> 16;
  return (short)r;
}

// ---------------- RoPE cos/sin table: [SLEN][64] ----------------
__global__ void rope_tab_k(f32x2* __restrict__ tab) {
  int i = blockIdx.x * blockDim.x + threadIdx.x;
  if (i >= SLEN * 64) return;
  int s = i >> 6, j = i & 63;
  float freq = exp2f(-(float)j * (13.287712379549449f / 64.0f));
  float ang = (float)s * freq;
  float sv, cv;
  sincosf(ang, &sv, &cv);
  f32x2 cs; cs[0] = cv; cs[1] = sv;
  tab[i] = cs;
}

// ---------------- fp32 -> bf16 cast (vectorized) ----------------
__global__ void cast_bf16_k(const float* __restrict__ in, short* __restrict__ outp, int n) {
  int i = (blockIdx.x * blockDim.x + threadIdx.x) * 4;
  if (i >= n) return;
  f32x4 v = *(const f32x4*)(in + i);
  s16x4 r;
#pragma unroll
  for (int k = 0; k < 4; ++k) r[k] = f2bf(v[k]);
  *(s16x4*)(outp + i) = r;
}

// ---------------- transpose + cast: in (R,C) fp32 -> out (C,R) bf16 ----------------
__global__ void transpose_cast_k(const float* __restrict__ in, short* __restrict__ outp,
                                 int R, int C) {
  __shared__ float t[32][33];
  int c0 = blockIdx.x * 32, r0 = blockIdx.y * 32;
  int tx = threadIdx.x, ty = threadIdx.y; // 32 x 8
#pragma unroll
  for (int i = 0; i < 4; ++i)
    t[ty + i * 8][tx] = in[(size_t)(r0 + ty + i * 8) * C + (c0 + tx)];
  __syncthreads();
#pragma unroll
  for (int i = 0; i < 4; ++i)
    outp[(size_t)(c0 + ty + i * 8) * R + (r0 + tx)] = f2bf(t[tx][ty + i * 8]);
}

// ---------------- GEMM: C(M,N) = A(M,K) * Bt(N,K)^T, bf16 MFMA ----------------
#define BM 128
#define BN 128
#define BK 32

#define GLL16(g, l)                                                        \
  __builtin_amdgcn_global_load_lds(                                        \
      (const __attribute__((address_space(1))) void*)(g),                  \
      (__attribute__((address_space(3))) void*)(l), 16, 0, 0)

// EPI: 0 = fp32 store to Cf (row-major M x N)
//      5 = fused QKV epilogue: gc<2048 Q (RoPE+scale), gc<2560 K (RoPE),
//          else V (transposed store). All three regions tile-aligned (128),
//          so the path is uniform per wave instruction; __shfl_xor safe.
template <int EPI>
__global__ __launch_bounds__(256, 2) void gemm_bt_k(
    const short* __restrict__ A, const short* __restrict__ Bt,
    float* __restrict__ Cf, short* __restrict__ Cb,
    int M, int N, int K, const f32x2* __restrict__ rope) {
  __shared__ short lA[2][BM * BK];
  __shared__ short lB[2][BN * BK];
  int tid = threadIdx.x;
  int lane = tid & 63, wid = tid >> 6;
  int m0 = blockIdx.y * BM, n0 = blockIdx.x * BN;
  int wr = (wid >> 1) * 64, wc = (wid & 1) * 64;
  int l16 = lane & 15, lk = (lane >> 4) * 8;
  (void)M;

  auto stage = [&](int buf, int k0) {
    const short* ga = A + (size_t)m0 * K + k0;
    const short* gb = Bt + (size_t)n0 * K + k0;
#pragma unroll
    for (int i = 0; i < 2; ++i) {
      int cidx = i * 256 + tid;
      int row = cidx >> 2, c8 = (cidx & 3) << 3;
      GLL16(ga + (size_t)row * K + c8, &lA[buf][(size_t)(i * 256 + (tid & 192)) * 8]);
      GLL16(gb + (size_t)row * K + c8, &lB[buf][(size_t)(i * 256 + (tid & 192)) * 8]);
    }
  };

  f32x4 acc[4][4] = {};
  stage(0, 0);
  asm volatile("s_waitcnt vmcnt(0)" ::: "memory");
  __syncthreads();
  int nk = K / BK;
  for (int t = 0; t < nk; ++t) {
    int buf = t & 1;
    if (t + 1 < nk) stage(buf ^ 1, (t + 1) * BK);
    bf16x8 af[4], bfv[4];
#pragma unroll
    for (int m = 0; m < 4; ++m)
      af[m] = *(const bf16x8*)&lA[buf][(wr + m * 16 + l16) * BK + lk];
#pragma unroll
    for (int n = 0; n < 4; ++n)
      bfv[n] = *(const bf16x8*)&lB[buf][(wc + n * 16 + l16) * BK + lk];
#pragma unroll
    for (int m = 0; m < 4; ++m)
#pragma unroll
      for (int n = 0; n < 4; ++n)
        acc[m][n] = __builtin_amdgcn_mfma_f32_16x16x32_bf16(af[m], bfv[n], acc[m][n], 0, 0, 0);
    asm volatile("s_waitcnt vmcnt(0)" ::: "memory");
    __syncthreads();
  }

  const float SCL2E = 0.08838834764831845f * 1.4426950408889634f;
  // epilogue: C/D layout col = lane&15, row = (lane>>4)*4 + reg
#pragma unroll
  for (int m = 0; m < 4; ++m) {
#pragma unroll
    for (int n = 0; n < 4; ++n) {
#pragma unroll
      for (int j = 0; j < 4; ++j) {
        int gm = m0 + wr + m * 16 + (lane >> 4) * 4 + j;
        int gc = n0 + wc + n * 16 + l16;
        float v = acc[m][n][j];
        if constexpr (EPI == 0) {
          Cf[(size_t)gm * N + gc] = v;
        } else { // EPI == 5: fused QKV
          int pos = gm & (SLEN - 1), bb = gm >> 11;
          if (gc < 2560) { // Q or K: RoPE
            float p = __shfl_xor(v, 1); // partner column (d^1), same row
            bool isq = gc < 2048;
            int gcc = isq ? gc : gc - 2048;
            int head = gcc >> 7, d = gcc & 127, j2 = d >> 1;
            f32x2 cs = rope[pos * 64 + j2];
            float ov; int od;
            if ((d & 1) == 0) { ov = v * cs[0] - p * cs[1]; od = j2; }
            else              { ov = p * cs[1] + v * cs[0]; od = j2 + 64; }
            if (isq) ov *= SCL2E; // fold attn scale*log2e into Q
            size_t idx = isq
                ? (((size_t)(bb * NH + head) * SLEN + pos) * HD + od)
                : ((size_t)QOFF + ((size_t)(bb * NKV + head) * SLEN + pos) * HD + od);
            Cb[idx] = f2bf(ov);
          } else { // V: transposed per (b,kv): [HD][S]
            int gcc = gc - 2560;
            int head = gcc >> 7, d = gcc & 127;
            Cb[(size_t)QOFF + KOFF + ((size_t)(bb * NKV + head) * HD + d) * SLEN + pos] = f2bf(v);
          }
        }
      }
    }
  }
}

// ---------------- flash attention, LDS-cooperative swapped-operand form ----
// 8 waves/block (512 thr), QBLK=128 (16 q-rows/wave), KVBLK=64.
// K and V tiles double-buffered in LDS via global_load_lds (linear dest,
// inverse-swizzled global source, XOR-swizzled ds_read: rule #21).
// K rows are 256B -> 4-bit row swizzle ((row&15)<<4): 4-way conflicts (was
// 8-way with 3 bits). V rows are 128B -> only 3 bits available.
// QK^T swapped (mfma(K,Q)) -> in-lane softmax; PV swapped -> lane-local q.
// P through per-wave LDS with lgkmcnt fence (R3 NaN lesson, rule #18).
// T5: setprio(1) around both MFMA clusters.
__global__ __launch_bounds__(512, 3) void flash_k(
    const short* __restrict__ Qb, const short* __restrict__ Kb,
    const short* __restrict__ Vt, short* __restrict__ O) {
  __shared__ short lK[2][64 * 128];   // 64 key rows x 256B
  __shared__ short lV[2][128 * 64];   // 128 dim rows x 128B
  __shared__ short Plds[8][16][64];   // per-wave P: 16 rows x 128B

  int tid = threadIdx.x, lane = tid & 63, wid = tid >> 6;
  int bh = blockIdx.y;
  int b = bh >> 4, h = bh & 15, kv = h & 3; // jnp.tile => h % NKV
  int l16 = lane & 15, lk4 = lane >> 4;
  int qt = (SLEN / 128 - 1) - blockIdx.x; // heavy tiles first
  int qbw = qt * 128 + wid * 16;          // this wave's q-row base

  const short* qptr = Qb + (size_t)(b * NH + h) * SLEN * HD;
  const char* kg = (const char*)(Kb + (size_t)(b * NKV + kv) * SLEN * HD);
  const char* vg = (const char*)(Vt + (size_t)(b * NKV + kv) * HD * SLEN);

  bf16x8 aq[4];
#pragma unroll
  for (int c = 0; c < 4; ++c)
    aq[c] = *(const bf16x8*)(qptr + (size_t)(qbw + l16) * HD + c * 32 + lk4 * 8);

  f32x4 o[8] = {};
  float m = -__builtin_inff();
  float lsum = 0.0f;

  char* myP = (char*)&Plds[wid][0][0];
  int swz = (l16 & 7) << 4;   // 3-bit (P and V: 128B rows)
  int swzk = l16 << 4;        // 4-bit (K: 256B rows)

  auto stageKV = [&](int buf, int k0) {
#pragma unroll
    for (int r = 0; r < 2; ++r) { // K: 16KB = 2 rounds x 512 thr x 16B
      int X = tid * 16 + r * 8192;
      int row = X >> 8, cb = X & 255;
      GLL16(kg + (size_t)(k0 + row) * 256 + (cb ^ ((row & 15) << 4)),
            (char*)&lK[buf][0] + X);
    }
#pragma unroll
    for (int r = 0; r < 2; ++r) { // V: 16KB
      int X = tid * 16 + r * 8192;
      int row = X >> 7, cb = X & 127;
      GLL16(vg + (size_t)row * (SLEN * 2) + k0 * 2 + (cb ^ ((row & 7) << 4)),
            (char*)&lV[buf][0] + X);
    }
  };

  int ntiles = 2 * (qt + 1); // block kend = (qt+1)*128
  stageKV(0, 0);
  asm volatile("s_waitcnt vmcnt(0)" ::: "memory");
  __syncthreads();

  for (int tt = 0; tt < ntiles; ++tt) {
    int buf = tt & 1;
    int k0 = tt * 64;
    if (tt + 1 < ntiles) stageKV(buf ^ 1, (tt + 1) * 64);

    if (k0 < qbw + 16) { // this wave still has unmasked keys in this tile
      const char* Kbase = (const char*)&lK[buf][0];
      const char* Vbase = (const char*)&lV[buf][0];
      // ---- QK^T (swapped): s[t][j] = S[key=k0+t*16+lk4*4+j][q=qbw+l16] ----
      f32x4 s[4] = {};
      __builtin_amdgcn_s_setprio(1);
#pragma unroll
      for (int c = 0; c < 4; ++c) {
#pragma unroll
        for (int t = 0; t < 4; ++t) {
          bf16x8 bk = *(const bf16x8*)(Kbase + (t * 16 + l16) * 256 + ((c * 64 + lk4 * 16) ^ swzk));
          s[t] = __builtin_amdgcn_mfma_f32_16x16x32_bf16(bk, aq[c], s[t], 0, 0, 0);
        }
      }
      __builtin_amdgcn_s_setprio(0);
      // ---- in-lane softmax ----
      float x[16];
#pragma unroll
      for (int t = 0; t < 4; ++t)
#pragma unroll
        for (int j = 0; j < 4; ++j) x[t * 4 + j] = s[t][j];
      if (k0 + 63 > qbw) { // tile touches this wave's causal diagonal
        int kq = k0 + lk4 * 4 - qbw - l16;
#pragma unroll
        for (int t = 0; t < 4; ++t)
#pragma unroll
          for (int j = 0; j < 4; ++j)
            if (kq + t * 16 + j > 0) x[t * 4 + j] = -3.0e38f;
      }
      float a0 = fmaxf(x[0], x[1]), a1 = fmaxf(x[2], x[3]);
      float a2 = fmaxf(x[4], x[5]), a3 = fmaxf(x[6], x[7]);
      float a4 = fmaxf(x[8], x[9]), a5 = fmaxf(x[10], x[11]);
      float a6 = fmaxf(x[12], x[13]), a7 = fmaxf(x[14], x[15]);
      float b0 = fmaxf(fmaxf(a0, a1), fmaxf(a2, a3));
      float b1 = fmaxf(fmaxf(a4, a5), fmaxf(a6, a7));
      float tm = fmaxf(b0, b1);
      tm = fmaxf(tm, __shfl_xor(tm, 16));
      tm = fmaxf(tm, __shfl_xor(tm, 32));
      float mn = fmaxf(m, tm);
      if (!__all(tm <= m + 8.0f)) { // T13 defer-rescale
        float f = __builtin_amdgcn_exp2f(m - mn);
        m = mn;
        lsum *= f;
#pragma unroll
        for (int dt = 0; dt < 8; ++dt) o[dt] *= f;
      }
      float psum = 0.0f;
#pragma unroll
      for (int t = 0; t < 4; ++t) {
        float p0 = __builtin_amdgcn_exp2f(x[t * 4 + 0] - m);
        float p1 = __builtin_amdgcn_exp2f(x[t * 4 + 1] - m);
        float p2 = __builtin_amdgcn_exp2f(x[t * 4 + 2] - m);
        float p3 = __builtin_amdgcn_exp2f(x[t * 4 + 3] - m);
        psum += (p0 + p1) + (p2 + p3);
        unsigned lo, hi;
        asm("v_cvt_pk_bf16_f32 %0, %1, %2" : "=v"(lo) : "v"(p0), "v"(p1));
        asm("v_cvt_pk_bf16_f32 %0, %1, %2" : "=v"(hi) : "v"(p2), "v"(p3));
        unsigned long long dw = ((unsigned long long)hi << 32) | lo;
        *(unsigned long long*)(myP + ((l16 * 128 + t * 32 + lk4 * 8) ^ swz)) = dw;
      }
      lsum += psum;
      // ---- ORDERING FENCE (rule #18): drain P ds_writes, pin reads below --
      asm volatile("s_waitcnt lgkmcnt(0)" ::: "memory");
      __builtin_amdgcn_sched_barrier(0);
      // ---- PV (swapped): o[dt][j] = O[q=qbw+l16][d=dt*16+lk4*4+j] ----
      __builtin_amdgcn_s_setprio(1);
#pragma unroll
      for (int hh = 0; hh < 2; ++hh) {
        bf16x8 pa = *(const bf16x8*)(myP + ((l16 * 128 + hh * 64 + lk4 * 16) ^ swz));
#pragma unroll
        for (int dt = 0; dt < 8; ++dt) {
          bf16x8 bv = *(const bf16x8*)(Vbase + (dt * 16 + l16) * 128 + ((hh * 64 + lk4 * 16) ^ swz));
          o[dt] = __builtin_amdgcn_mfma_f32_16x16x32_bf16(bv, pa, o[dt], 0, 0, 0);
        }
      }
      __builtin_amdgcn_s_setprio(0);
    }
    asm volatile("s_waitcnt vmcnt(0)" ::: "memory");
    __syncthreads();
  }
  // ---- finalize: reduce deferred partial sums across the 4 key-groups ----
  lsum += __shfl_xor(lsum, 16);
  lsum += __shfl_xor(lsum, 32);
  float inv = 1.0f / lsum;
  size_t ro = ((size_t)(b * SLEN + qbw + l16)) * (NH * HD) + h * HD;
#pragma unroll
  for (int dt = 0; dt < 8; ++dt) {
    s16x4 r;
#pragma unroll
    for (int j = 0; j < 4; ++j) r[j] = f2bf(o[dt][j] * inv);
    *(s16x4*)(O + ro + dt * 16 + lk4 * 4) = r;
  }
}

extern "C" void kernel_launch(void* const* d_in, const int* in_sizes, int n_in,
                              void* d_out, int out_size, void* d_ws, size_t ws_size,
                              hipStream_t stream) {
  const float* x  = (const float*)d_in[0];
  const float* wq = (const float*)d_in[1];
  const float* wk = (const float*)d_in[2];
  const float* wv = (const float*)d_in[3];
  const float* wo = (const float*)d_in[4];
  float* out = (float*)d_out;
  char* ws = (char*)d_ws;
  (void)in_sizes; (void)n_in; (void)out_size; (void)ws_size;

  const size_t MB = 1024 * 1024;
  f32x2* rope   = (f32x2*)(ws);          // 1 MB
  short* xb     = (short*)(ws + 1 * MB); // 16 MB (reused as O)
  short* wqkvT  = (short*)(ws + 17 * MB);// 12 MB: [3072][2048] bf16 B^T
  short* woT    = (short*)(ws + 29 * MB);// 8 MB
  short* QKVb   = (short*)(ws + 37 * MB);// 24 MB: Q(16) + K(4) + V(4)
  short* O      = xb;                    // alias: xb dead after QKV GEMM

  short* Qb = QKVb;
  short* Kb = QKVb + QOFF;
  short* Vt = QKVb + QOFF + KOFF;

  rope_tab_k<<<(SLEN * 64 + 255) / 256, 256, 0, stream>>>(rope);
  cast_bf16_k<<<(MROWS * EMB / 4 + 255) / 256, 256, 0, stream>>>(x, xb, MROWS * EMB);

  dim3 tb(32, 8);
  transpose_cast_k<<<dim3(2048 / 32, 2048 / 32), tb, 0, stream>>>(wq, wqkvT, 2048, 2048);
  transpose_cast_k<<<dim3(512 / 32, 2048 / 32), tb, 0, stream>>>(wk, wqkvT + 2048 * 2048, 2048, 512);
  transpose_cast_k<<<dim3(512 / 32, 2048 / 32), tb, 0, stream>>>(wv, wqkvT + 2560 * 2048, 2048, 512);
  transpose_cast_k<<<dim3(2048 / 32, 2048 / 32), tb, 0, stream>>>(wo, woT, 2048, 2048);

  gemm_bt_k<5><<<dim3(3072 / BN, MROWS / BM), 256, 0, stream>>>(xb, wqkvT, nullptr, QKVb, MROWS, 3072, 2048, rope);

  flash_k<<<dim3(SLEN / 128, BSZ * NH), 512, 0, stream>>>(Qb, Kb, Vt, O);

  gemm_bt_k<0><<<dim3(2048 / BN, MROWS / BM), 256, 0, stream>>>(O, woT, out, nullptr, MROWS, 2048, 2048, rope);
}